// Round 1
// baseline (6577.284 us; speedup 1.0000x reference)
//
#include <hip/hip_runtime.h>

// Problem constants (match reference setup_inputs)
#define NS 8192
#define L  50
#define LP 64     // padded node count
#define D  300    // embed dim
#define H1 150    // SAGE hidden
#define O  64     // SAGE out
// LDS layout: embT (bf16 [300][68]) | tbuf (bf16 [150][68]) | misc
// st2 (f32 [128][68]) aliases embT once it is dead; red[4][64] aliases tbuf early.
#define ESTR 68          // row stride (elements) -> 136B rows, 8B aligned, 4-way-max bank spread
#define T_OFF 40800      // 300*68*2
#define MISC_OFF 61200   // 40800 + 150*68*2
#define SMEM_BYTES 62736

typedef unsigned short u16;
typedef unsigned int   u32;

__device__ __forceinline__ u16 f2bf(float f) {
  u32 u = __float_as_uint(f);
  u += 0x7fffu + ((u >> 16) & 1u);   // RNE
  return (u16)(u >> 16);
}
__device__ __forceinline__ float bf2f(u16 h) {
  return __uint_as_float(((u32)h) << 16);
}
__device__ __forceinline__ void unpack4(uint2 p, float* o) {
  o[0] = __uint_as_float(p.x << 16);
  o[1] = __uint_as_float(p.x & 0xffff0000u);
  o[2] = __uint_as_float(p.y << 16);
  o[3] = __uint_as_float(p.y & 0xffff0000u);
}

struct GParams {
  const int* words; const int* syn_words; const int* syn_adj;
  const float* embed;
  const float* sem_W1s; const float* sem_W1n; const float* sem_b1;
  const float* sem_W2s; const float* sem_W2n; const float* sem_b2;
  const float* sem_gw;  const float* sem_gb;
  const float* syn_W1s; const float* syn_W1n; const float* syn_b1;
  const float* syn_W2s; const float* syn_W2n; const float* syn_b2;
  const float* syn_gw;  const float* syn_gb;
  float* semf; float* synf;
};

// One block per (sentence, graph). blocks [0,NS) = semantic, [NS,2NS) = syntax.
__global__ __launch_bounds__(256, 2) void sage_kernel(GParams P) {
  __shared__ __align__(16) char smem[SMEM_BYTES];
  u16*   embT  = (u16*)(smem);                  // [D][ESTR] bf16
  u16*   tbuf  = (u16*)(smem + T_OFF);          // [H1][ESTR] bf16 (t -> agg -> h1T)
  float* red   = (float*)(smem + T_OFF);        // [4][64] alias (norm reduce, early)
  float* st2   = (float*)(smem);                // [128][ESTR] f32, alias embT (dead)
  int*      wid   = (int*)(smem + MISC_OFF);
  float*    rnorm = (float*)(smem + MISC_OFF + 256);
  float*    rdeg  = (float*)(smem + MISC_OFF + 512);
  unsigned* clo   = (unsigned*)(smem + MISC_OFF + 768);
  unsigned* chi   = (unsigned*)(smem + MISC_OFF + 1024);
  float*    attn  = (float*)(smem + MISC_OFF + 1280);

  const int tid = threadIdx.x;
  const bool semg = (blockIdx.x < NS);
  const int n = semg ? blockIdx.x : (blockIdx.x - NS);

  const int*   wsrc = semg ? P.words   : P.syn_words;
  const float* W1s  = semg ? P.sem_W1s : P.syn_W1s;
  const float* W1n  = semg ? P.sem_W1n : P.syn_W1n;
  const float* b1   = semg ? P.sem_b1  : P.syn_b1;
  const float* W2s  = semg ? P.sem_W2s : P.syn_W2s;
  const float* W2n  = semg ? P.sem_W2n : P.syn_W2n;
  const float* b2   = semg ? P.sem_b2  : P.syn_b2;
  const float* gw   = semg ? P.sem_gw  : P.syn_gw;
  const float* gb   = semg ? P.sem_gb  : P.syn_gb;
  float* featout    = semg ? P.semf    : P.synf;

  // ---- phase 0: word ids + mask init ----
  if (tid < LP) {
    int w = (tid < L) ? wsrc[(size_t)n * L + tid] : 0;
    wid[tid] = w;
    clo[tid] = 0u; chi[tid] = 0u;
  }
  __syncthreads();

  // ---- phase 1: gather embT[d][v] (bf16). pad/invalid rows -> 0 (masked later) ----
  for (int v = 0; v < LP; ++v) {
    int w = wid[v];
    const float* src = P.embed + (size_t)w * D;
    for (int d = tid; d < D; d += 256) {
      float val = (w > 0) ? src[d] : 0.0f;
      embT[d * ESTR + v] = f2bf(val);
    }
  }
  __syncthreads();

  // ---- phase 2/3: adjacency column masks ----
  if (semg) {
    // norms: wave wv covers d-chunk, lane = node
    {
      const int wv = tid >> 6, lane = tid & 63;
      float s = 0.0f;
      const int d0 = wv * 75;
      for (int d = d0; d < d0 + 75; ++d) {
        float e = bf2f(embT[d * ESTR + lane]);
        s += e * e;
      }
      red[wv * 64 + lane] = s;
    }
    __syncthreads();
    if (tid < LP) {
      float s = red[tid] + red[64 + tid] + red[128 + tid] + red[192 + tid];
      rnorm[tid] = 1.0f / fmaxf(sqrtf(s), 1e-8f);
    }
    __syncthreads();
    // cos Gram: 16x16 thread tiles of 4x4 pairs
    {
      const int u0 = (tid >> 4) * 4;
      const int v0 = (tid & 15) * 4;
      float acc[4][4];
      #pragma unroll
      for (int i = 0; i < 4; ++i)
        #pragma unroll
        for (int j = 0; j < 4; ++j) acc[i][j] = 0.0f;
      for (int d = 0; d < D; ++d) {
        float eu[4], ev[4];
        unpack4(*(const uint2*)&embT[d * ESTR + u0], eu);
        unpack4(*(const uint2*)&embT[d * ESTR + v0], ev);
        #pragma unroll
        for (int i = 0; i < 4; ++i)
          #pragma unroll
          for (int j = 0; j < 4; ++j) acc[i][j] += eu[i] * ev[j];
      }
      #pragma unroll
      for (int j = 0; j < 4; ++j) {
        unsigned nib = 0;
        #pragma unroll
        for (int i = 0; i < 4; ++i) {
          const int u = u0 + i, v = v0 + j;
          float c = acc[i][j] * rnorm[u] * rnorm[v];
          bool ok = (c > 0.7f) && (wid[u] > 0) && (wid[v] > 0);
          nib |= ok ? (1u << i) : 0u;
        }
        if (nib) {
          if (u0 < 32) atomicOr(&clo[v0 + j], nib << u0);
          else         atomicOr(&chi[v0 + j], nib << (u0 - 32));
        }
      }
    }
  } else {
    // syntax adjacency (already masked in setup); bit u of column v
    if (tid < L) {
      const int v = tid;
      unsigned lo = 0, hi = 0;
      const int* arow = P.syn_adj + (size_t)n * L * L;
      for (int u = 0; u < L; ++u) {
        if (arow[u * L + v] != 0) {
          if (u < 32) lo |= 1u << u; else hi |= 1u << (u - 32);
        }
      }
      clo[v] = lo; chi[v] = hi;
    }
  }
  __syncthreads();

  // ---- phase 4: 1/deg ----
  if (tid < LP) {
    int dg = __popc(clo[tid]) + __popc(chi[tid]);
    rdeg[tid] = 1.0f / (float)((dg > 1) ? dg : 1);
  }
  __syncthreads();

  const int vt  = tid >> 6;    // 0..3  (16 rows each)
  const int jt  = tid & 63;
  const int v0g = vt * 16;

  // ---- phase 5: t = emb @ W1n  -> tbuf (bf16, transposed [col][v]) ----
  {
    float acc[3][16];
    #pragma unroll
    for (int k = 0; k < 3; ++k)
      #pragma unroll
      for (int i = 0; i < 16; ++i) acc[k][i] = 0.0f;
    for (int d = 0; d < D; ++d) {
      float e[16];
      const uint2* pe = (const uint2*)&embT[d * ESTR + v0g];
      unpack4(pe[0], e); unpack4(pe[1], e + 4); unpack4(pe[2], e + 8); unpack4(pe[3], e + 12);
      const float* wr = W1n + (size_t)d * H1;
      float w0 = wr[jt];
      float w1 = wr[jt + 64];
      float w2 = (jt < H1 - 128) ? wr[jt + 128] : 0.0f;
      #pragma unroll
      for (int i = 0; i < 16; ++i) {
        acc[0][i] += e[i] * w0;
        acc[1][i] += e[i] * w1;
        acc[2][i] += e[i] * w2;
      }
    }
    #pragma unroll
    for (int k = 0; k < 3; ++k) {
      int col = jt + 64 * k;
      if (col < H1) {
        #pragma unroll
        for (int i = 0; i < 16; ++i) tbuf[col * ESTR + v0g + i] = f2bf(acc[k][i]);
      }
    }
  }
  __syncthreads();

  // ---- phase 6: agg1 in-place: tbuf[j][v] = (sum_u A[u][v] t[j][u]) / deg[v] ----
  {
    const int wv = tid >> 6, lane = tid & 63;
    const unsigned mlo = clo[lane], mhi = chi[lane];
    const float rd = rdeg[lane];
    for (int j = wv; j < H1; j += 4) {       // row j owned by exactly one wave
      float a = 0.0f;
      unsigned m = mlo;
      while (m) { int u = __ffs(m) - 1; m &= m - 1; a += bf2f(tbuf[j * ESTR + u]); }
      m = mhi;
      while (m) { int u = __ffs(m) - 1; m &= m - 1; a += bf2f(tbuf[j * ESTR + 32 + u]); }
      tbuf[j * ESTR + lane] = f2bf(a * rd);  // write after all reads (wave-synchronous)
    }
  }
  __syncthreads();

  // ---- phase 7: h1 = relu(emb@W1s + agg + b1) -> tbuf (bf16) ----
  {
    float acc[3][16];
    #pragma unroll
    for (int k = 0; k < 3; ++k) {
      int col = jt + 64 * k;
      if (col < H1) {
        float bb = b1[col];
        #pragma unroll
        for (int i = 0; i < 16; ++i) acc[k][i] = bb + bf2f(tbuf[col * ESTR + v0g + i]);
      } else {
        #pragma unroll
        for (int i = 0; i < 16; ++i) acc[k][i] = 0.0f;
      }
    }
    __syncthreads();   // all agg reads done before any h1 overwrite
    for (int d = 0; d < D; ++d) {
      float e[16];
      const uint2* pe = (const uint2*)&embT[d * ESTR + v0g];
      unpack4(pe[0], e); unpack4(pe[1], e + 4); unpack4(pe[2], e + 8); unpack4(pe[3], e + 12);
      const float* wr = W1s + (size_t)d * H1;
      float w0 = wr[jt];
      float w1 = wr[jt + 64];
      float w2 = (jt < H1 - 128) ? wr[jt + 128] : 0.0f;
      #pragma unroll
      for (int i = 0; i < 16; ++i) {
        acc[0][i] += e[i] * w0;
        acc[1][i] += e[i] * w1;
        acc[2][i] += e[i] * w2;
      }
    }
    #pragma unroll
    for (int k = 0; k < 3; ++k) {
      int col = jt + 64 * k;
      if (col < H1) {
        #pragma unroll
        for (int i = 0; i < 16; ++i)
          tbuf[col * ESTR + v0g + i] = f2bf(fmaxf(acc[k][i], 0.0f));
      }
    }
  }
  __syncthreads();

  // ---- phase 8: s2 = h1@W2s, t2 = h1@W2n -> st2 rows [0..63]=s2, [64..127]=t2 (f32) ----
  {
    float a0[16], a1[16];
    #pragma unroll
    for (int i = 0; i < 16; ++i) { a0[i] = 0.0f; a1[i] = 0.0f; }
    for (int d = 0; d < H1; ++d) {
      float e[16];
      const uint2* pe = (const uint2*)&tbuf[d * ESTR + v0g];
      unpack4(pe[0], e); unpack4(pe[1], e + 4); unpack4(pe[2], e + 8); unpack4(pe[3], e + 12);
      float w0 = W2s[(size_t)d * O + jt];
      float w1 = W2n[(size_t)d * O + jt];
      #pragma unroll
      for (int i = 0; i < 16; ++i) { a0[i] += e[i] * w0; a1[i] += e[i] * w1; }
    }
    float4* ps = (float4*)&st2[jt * ESTR + v0g];
    float4* pt = (float4*)&st2[(64 + jt) * ESTR + v0g];
    #pragma unroll
    for (int q = 0; q < 4; ++q) {
      ps[q] = make_float4(a0[4*q], a0[4*q+1], a0[4*q+2], a0[4*q+3]);
      pt[q] = make_float4(a1[4*q], a1[4*q+1], a1[4*q+2], a1[4*q+3]);
    }
  }
  __syncthreads();

  // ---- phase 9: h2 = s2 + agg(t2) + b2, in-place into st2 rows [0..63] ----
  {
    const int wv = tid >> 6, lane = tid & 63;
    const unsigned mlo = clo[lane], mhi = chi[lane];
    const float rd = rdeg[lane];
    for (int j2 = wv; j2 < O; j2 += 4) {
      float a = 0.0f;
      unsigned m = mlo;
      while (m) { int u = __ffs(m) - 1; m &= m - 1; a += st2[(64 + j2) * ESTR + u]; }
      m = mhi;
      while (m) { int u = __ffs(m) - 1; m &= m - 1; a += st2[(64 + j2) * ESTR + 32 + u]; }
      st2[j2 * ESTR + lane] = st2[j2 * ESTR + lane] + a * rd + b2[j2];
    }
  }
  __syncthreads();

  // ---- phase 10: gate + masked softmax (wave 0) ----
  if (tid < 64) {
    const int v = tid;
    float g = 0.0f;
    for (int j2 = 0; j2 < O; ++j2) g += st2[j2 * ESTR + v] * gw[j2];
    g += gb[0];
    const bool val = (wid[v] > 0);
    g = val ? g : -1e30f;
    float mx = g;
    #pragma unroll
    for (int off = 32; off; off >>= 1) mx = fmaxf(mx, __shfl_xor(mx, off));
    float e = val ? __expf(g - mx) : 0.0f;
    float s = e;
    #pragma unroll
    for (int off = 32; off; off >>= 1) s += __shfl_xor(s, off);
    attn[v] = e / s;
  }
  __syncthreads();

  // ---- phase 11: pooled feature: out[o] = sum_v attn[v] * h2[v][o] ----
  {
    const int wv = tid >> 6, lane = tid & 63;
    const float av = attn[lane];
    for (int o = wv; o < O; o += 4) {
      float x = av * st2[o * ESTR + lane];
      #pragma unroll
      for (int off = 32; off; off >>= 1) x += __shfl_xor(x, off);
      if (lane == 0) featout[(size_t)n * O + o] = x;
    }
  }
}

// Classifier: feat=[sem|syn|hsg] (192) -> relu(192x128) -> 128x2
__global__ __launch_bounds__(128) void cls_kernel(const float* semf, const float* synf,
                                                  const float* hsg,
                                                  const float* w1, const float* b1,
                                                  const float* w2, const float* b2,
                                                  float* out) {
  __shared__ float feat[32][192];
  __shared__ float hid[32][132];   // padded stride to spread banks
  const int r0 = blockIdx.x * 32;
  for (int idx = threadIdx.x; idx < 32 * 192; idx += 128) {
    int r = idx / 192, c = idx % 192;
    float v;
    if (c < 64)        v = semf[(size_t)(r0 + r) * 64 + c];
    else if (c < 128)  v = synf[(size_t)(r0 + r) * 64 + (c - 64)];
    else               v = hsg [(size_t)(r0 + r) * 64 + (c - 128)];
    feat[r][c] = v;
  }
  __syncthreads();
  {
    const int j = threadIdx.x;  // 0..127 hidden unit
    float acc[32];
    float bb = b1[j];
    #pragma unroll
    for (int r = 0; r < 32; ++r) acc[r] = bb;
    for (int k = 0; k < 192; ++k) {
      float w = w1[(size_t)k * 128 + j];
      #pragma unroll
      for (int r = 0; r < 32; ++r) acc[r] += feat[r][k] * w;
    }
    #pragma unroll
    for (int r = 0; r < 32; ++r) hid[r][j] = fmaxf(acc[r], 0.0f);
  }
  __syncthreads();
  if (threadIdx.x < 64) {
    const int r = threadIdx.x >> 1, o = threadIdx.x & 1;
    float a = b2[o];
    for (int h = 0; h < 128; ++h) a += hid[r][h] * w2[h * 2 + o];
    out[(size_t)(r0 + r) * 2 + o] = a;
  }
}

extern "C" void kernel_launch(void* const* d_in, const int* in_sizes, int n_in,
                              void* d_out, int out_size, void* d_ws, size_t ws_size,
                              hipStream_t stream) {
  GParams P;
  P.words     = (const int*)d_in[0];
  P.syn_words = (const int*)d_in[1];
  P.syn_adj   = (const int*)d_in[2];
  const float* hsg = (const float*)d_in[3];
  P.embed   = (const float*)d_in[4];
  P.sem_W1s = (const float*)d_in[5];
  P.sem_W1n = (const float*)d_in[6];
  P.sem_b1  = (const float*)d_in[7];
  P.sem_W2s = (const float*)d_in[8];
  P.sem_W2n = (const float*)d_in[9];
  P.sem_b2  = (const float*)d_in[10];
  P.sem_gw  = (const float*)d_in[11];
  P.sem_gb  = (const float*)d_in[12];
  P.syn_W1s = (const float*)d_in[13];
  P.syn_W1n = (const float*)d_in[14];
  P.syn_b1  = (const float*)d_in[15];
  P.syn_W2s = (const float*)d_in[16];
  P.syn_W2n = (const float*)d_in[17];
  P.syn_b2  = (const float*)d_in[18];
  P.syn_gw  = (const float*)d_in[19];
  P.syn_gb  = (const float*)d_in[20];
  const float* cls_w1 = (const float*)d_in[21];
  const float* cls_b1 = (const float*)d_in[22];
  const float* cls_w2 = (const float*)d_in[23];
  const float* cls_b2 = (const float*)d_in[24];

  float* semf = (float*)d_ws;                       // [NS][O]
  float* synf = semf + (size_t)NS * O;              // [NS][O]  (4 MB total)
  P.semf = semf; P.synf = synf;

  sage_kernel<<<2 * NS, 256, 0, stream>>>(P);
  cls_kernel<<<NS / 32, 128, 0, stream>>>(semf, synf, hsg, cls_w1, cls_b1,
                                          cls_w2, cls_b2, (float*)d_out);
}

// Round 2
// 1127.558 us; speedup vs baseline: 5.8332x; 5.8332x over previous
//
#include <hip/hip_runtime.h>

#define NS 8192
#define L  50

typedef unsigned short u16;
typedef unsigned int   u32;
typedef __attribute__((ext_vector_type(8))) __bf16 bf16x8;
typedef __attribute__((ext_vector_type(4))) float  f32x4;

// ---------------- LDS layout (bytes) ----------------
// live ranges:  X(gather,Gram,GEMM1) -> St(s-part) -> S2+T2t
//               Tt(t-part) -> H1 -> h2
#define OFF_X    0        // X bf16 [64][328] = 41984
#define OFF_ST   0        // St bf16 [160][72] = 23040 (alias; after GEMM1)
#define OFF_S2   0        // S2 f32 [64][66] = 16896 (alias; after GEMM2)
#define OFF_T2T  16896    // T2t bf16 [64][72] = 9216
#define OFF_TT   41984    // Tt bf16 [160][72] = 23040
#define OFF_H1   41984    // H1 bf16 [64][168] = 21504 (alias)
#define OFF_H2   41984    // h2 f32 [64][66] = 16896 (alias)
#define OFF_M    65024    // M bf16 [64][72] = 9216
#define OFF_WID  74240
#define OFF_CLO  74496
#define OFF_CHI  74752
#define OFF_RDEG 75008
#define OFF_DIAG 75264
#define OFF_ATTN 75520
#define OFF_RED  75776    // 4*64 f32
#define SMEM_SZ  76800    // -> 2 blocks/CU (153600 <= 160KB)

// padded weight tables in ws
#define W1_ROWS 320   // [0,150)=W1n cols, [160,310)=W1s cols, rest 0
#define W1_KP   328
#define W2_ROWS 128   // [0,64)=W2s cols, [64,128)=W2n cols
#define W2_KP   168

__device__ __forceinline__ u16 f2bf(float f) {
  u32 u = __float_as_uint(f);
  u += 0x7fffu + ((u >> 16) & 1u);   // RNE
  return (u16)(u >> 16);
}
__device__ __forceinline__ float bf2f(u16 h) {
  return __uint_as_float(((u32)h) << 16);
}
__device__ __forceinline__ f32x4 mfma16(bf16x8 a, bf16x8 b, f32x4 c) {
  return __builtin_amdgcn_mfma_f32_16x16x32_bf16(a, b, c, 0, 0, 0);
}

struct GParams {
  const int* words; const int* syn_words; const int* syn_adj;
  const float* embed;
  const float* sem_b1; const float* sem_b2; const float* sem_gw; const float* sem_gb;
  const float* syn_b1; const float* syn_b2; const float* syn_gw; const float* syn_gb;
  const u16* w1t_sem; const u16* w1t_syn; const u16* w2t_sem; const u16* w2t_syn;
  float* semf; float* synf;
};

// One block per (sentence, graph). [0,NS)=semantic, [NS,2NS)=syntax.
__global__ __launch_bounds__(256, 2) void sage_kernel(GParams P) {
  __shared__ __align__(16) char smem[SMEM_SZ];
  int*   wid  = (int*)(smem + OFF_WID);
  u32*   clo  = (u32*)(smem + OFF_CLO);
  u32*   chi  = (u32*)(smem + OFF_CHI);
  float* rdeg = (float*)(smem + OFF_RDEG);
  float* diag = (float*)(smem + OFF_DIAG);
  float* attn = (float*)(smem + OFF_ATTN);
  float* red  = (float*)(smem + OFF_RED);

  const int tid  = threadIdx.x;
  const int lane = tid & 63;
  const int w    = tid >> 6;
  const int ln   = lane & 15;
  const int quad = lane >> 4;

  const bool semg = (blockIdx.x < NS);
  const int  n    = semg ? blockIdx.x : (blockIdx.x - NS);

  const int*   wsrc = semg ? P.words   : P.syn_words;
  const u16*   W1T  = semg ? P.w1t_sem : P.w1t_syn;
  const u16*   W2T  = semg ? P.w2t_sem : P.w2t_syn;
  const float* b1g  = semg ? P.sem_b1  : P.syn_b1;
  const float* b2g  = semg ? P.sem_b2  : P.syn_b2;
  const float* gw   = semg ? P.sem_gw  : P.syn_gw;
  const float* gb   = semg ? P.sem_gb  : P.syn_gb;
  float* featout    = semg ? P.semf    : P.synf;

  // ---- phase 0: word ids + mask init ----
  if (tid < 64) {
    wid[tid] = (tid < L) ? wsrc[(size_t)n * L + tid] : 0;
    clo[tid] = 0u; chi[tid] = 0u;
  }
  __syncthreads();

  // ---- phase 1: gather X bf16 [64][328]; invalid rows & pad cols -> 0 ----
  for (int i = 0; i < 16; ++i) {
    const int v = w + 4 * i;          // wave w owns rows w,w+4,...
    const int word = wid[v];
    const float* src = P.embed + (size_t)word * 300;
    u16* xrow = (u16*)(smem + OFF_X) + v * 328;
    for (int l = lane; l < 82; l += 64) {
      uint2 pk = make_uint2(0u, 0u);
      if (word > 0 && l < 75) {
        float4 f = *(const float4*)(src + l * 4);   // rows 16B-aligned (1200B stride)
        pk.x = (u32)f2bf(f.x) | ((u32)f2bf(f.y) << 16);
        pk.y = (u32)f2bf(f.z) | ((u32)f2bf(f.w) << 16);
      }
      *(uint2*)(xrow + l * 4) = pk;
    }
  }
  __syncthreads();

  // ---- phase 2: adjacency column bitmasks ----
  if (semg) {
    // Gram = X @ X^T via MFMA; wave w computes row-tile mt=w, all 4 n-tiles
    const f32x4 z4 = {0.f, 0.f, 0.f, 0.f};
    f32x4 g[4] = {z4, z4, z4, z4};
    const char* xb = smem + OFF_X;
    const int arow = (w * 16 + ln) * 656 + quad * 16;
    for (int kk = 0; kk < 10; ++kk) {
      bf16x8 a = *(const bf16x8*)(xb + arow + kk * 64);
      #pragma unroll
      for (int nt = 0; nt < 4; ++nt) {
        bf16x8 b = *(const bf16x8*)(xb + (nt * 16 + ln) * 656 + quad * 16 + kk * 64);
        g[nt] = mfma16(a, b, g[nt]);
      }
    }
    // diagonal -> norms
    {
      const int r = ln - quad * 4;
      if (r >= 0 && r < 4) {
        #pragma unroll
        for (int nt = 0; nt < 4; ++nt) {
          if (nt == w) {
            float val = (r == 0) ? g[nt][0] : (r == 1) ? g[nt][1]
                      : (r == 2) ? g[nt][2] : g[nt][3];
            diag[w * 16 + ln] = val;
          }
        }
      }
    }
    __syncthreads();
    if (tid < 64) { float dd = diag[tid]; diag[tid] = 1.0f / sqrtf(fmaxf(dd, 1e-12f)); }
    __syncthreads();
    // threshold + column bitmask atomics  (u = row of C, v = col of C)
    {
      const int ubase = w * 16 + quad * 4;
      float ru[4]; int uok[4];
      #pragma unroll
      for (int r = 0; r < 4; ++r) { ru[r] = diag[ubase + r]; uok[r] = wid[ubase + r] > 0; }
      #pragma unroll
      for (int nt = 0; nt < 4; ++nt) {
        const int v = nt * 16 + ln;
        const float rv = diag[v];
        const bool vok = wid[v] > 0;
        u32 nib = 0u;
        #pragma unroll
        for (int r = 0; r < 4; ++r) {
          float c = g[nt][r] * ru[r] * rv;
          if (vok && uok[r] && c > 0.7f) nib |= (1u << r);
        }
        if (nib) {
          if (ubase < 32) atomicOr(&clo[v], nib << ubase);
          else            atomicOr(&chi[v], nib << (ubase - 32));
        }
      }
    }
  } else {
    // syntax: ballot over lane=u builds the column mask directly
    const int* abase = P.syn_adj + (size_t)n * (L * L);
    for (int v = w; v < L; v += 4) {
      int val = (lane < L) ? abase[lane * L + v] : 0;
      unsigned long long m = __ballot(val != 0);
      if (lane == 0) { clo[v] = (u32)m; chi[v] = (u32)(m >> 32); }
    }
  }
  __syncthreads();

  // ---- phase 3/4: 1/deg + adjacency matrix M[v][u] bf16 (for agg-GEMMs) ----
  if (tid < 64) {
    int dg = __popc(clo[tid]) + __popc(chi[tid]);
    rdeg[tid] = 1.0f / (float)(dg > 0 ? dg : 1);
  }
  {
    const int v = tid >> 2, part = tid & 3;
    const u32 lo = clo[v], hi = chi[v];
    u16* Mrow = (u16*)(smem + OFF_M) + v * 72;
    for (int u = part * 18; u < part * 18 + 18; ++u) {
      bool bit = (u < 32) ? ((lo >> u) & 1u) : ((u < 64) ? ((hi >> (u - 32)) & 1u) : false);
      Mrow[u] = bit ? (u16)0x3F80 : (u16)0;
    }
  }
  // (no barrier needed: M/rdeg consumed only after later barriers)

  // ---- phase 5: GEMM1  C1 = X @ [W1n | W1s]  (K=320, N=320) ----
  {
    const f32x4 z4 = {0.f, 0.f, 0.f, 0.f};
    f32x4 c1[5][4];
    #pragma unroll
    for (int t = 0; t < 5; ++t)
      #pragma unroll
      for (int m = 0; m < 4; ++m) c1[t][m] = z4;
    const char* xb = smem + OFF_X;
    for (int kk = 0; kk < 10; ++kk) {
      bf16x8 a[4];
      #pragma unroll
      for (int m = 0; m < 4; ++m)
        a[m] = *(const bf16x8*)(xb + (m * 16 + ln) * 656 + quad * 16 + kk * 64);
      bf16x8 b[5];
      #pragma unroll
      for (int t = 0; t < 5; ++t) {
        const int nrow = (w * 5 + t) * 16 + ln;
        b[t] = *(const bf16x8*)(W1T + nrow * 328 + kk * 32 + quad * 8);
      }
      #pragma unroll
      for (int t = 0; t < 5; ++t)
        #pragma unroll
        for (int m = 0; m < 4; ++m)
          c1[t][m] = mfma16(a[m], b[t], c1[t][m]);
    }
    __syncthreads();   // all X reads retired before overwriting X region with St
    #pragma unroll
    for (int t = 0; t < 5; ++t) {
      const int ntg = w * 5 + t;   // wave-uniform
      #pragma unroll
      for (int m = 0; m < 4; ++m) {
        const int v0 = m * 16 + quad * 4;
        uint2 pk;
        pk.x = (u32)f2bf(c1[t][m][0]) | ((u32)f2bf(c1[t][m][1]) << 16);
        pk.y = (u32)f2bf(c1[t][m][2]) | ((u32)f2bf(c1[t][m][3]) << 16);
        if (ntg < 10) {          // t-part, transposed: Tt[j][u]
          const int j = ntg * 16 + ln;
          *(uint2*)(smem + OFF_TT + (j * 72 + v0) * 2) = pk;
        } else {                 // s-part, transposed: St[j][u]
          const int j = (ntg - 10) * 16 + ln;
          *(uint2*)(smem + OFF_ST + (j * 72 + v0) * 2) = pk;
        }
      }
    }
  }
  __syncthreads();

  // ---- phase 6: aggGEMM1 h1n = M @ t  (K=64) ; h1 = relu(s + h1n*rdeg + b1) ----
  {
    const f32x4 z4 = {0.f, 0.f, 0.f, 0.f};
    f32x4 c6[10];
    #pragma unroll
    for (int t = 0; t < 10; ++t) c6[t] = z4;
    const char* mb = smem + OFF_M + ((w * 16 + ln) * 72 + quad * 8) * 2;
    bf16x8 a0 = *(const bf16x8*)(mb);
    bf16x8 a1 = *(const bf16x8*)(mb + 64);
    #pragma unroll
    for (int t = 0; t < 10; ++t) {
      const char* tb = smem + OFF_TT + ((t * 16 + ln) * 72 + quad * 8) * 2;
      bf16x8 b0 = *(const bf16x8*)(tb);
      bf16x8 b1f = *(const bf16x8*)(tb + 64);
      c6[t] = mfma16(a0, b0, c6[t]);
      c6[t] = mfma16(a1, b1f, c6[t]);
    }
    __syncthreads();   // Tt reads retired before H1 overwrites Tt
    const int v0 = w * 16 + quad * 4;
    float rd[4];
    #pragma unroll
    for (int r = 0; r < 4; ++r) rd[r] = rdeg[v0 + r];
    u16* h1p = (u16*)(smem + OFF_H1);
    #pragma unroll
    for (int t = 0; t < 10; ++t) {
      const int j = t * 16 + ln;
      uint2 sp = *(const uint2*)(smem + OFF_ST + (j * 72 + v0) * 2);
      float s0 = bf2f((u16)(sp.x & 0xffffu)), s1 = bf2f((u16)(sp.x >> 16));
      float s2 = bf2f((u16)(sp.y & 0xffffu)), s3 = bf2f((u16)(sp.y >> 16));
      const float bb = (j < 150) ? b1g[j] : 0.f;
      h1p[(v0 + 0) * 168 + j] = f2bf(fmaxf(s0 + c6[t][0] * rd[0] + bb, 0.f));
      h1p[(v0 + 1) * 168 + j] = f2bf(fmaxf(s1 + c6[t][1] * rd[1] + bb, 0.f));
      h1p[(v0 + 2) * 168 + j] = f2bf(fmaxf(s2 + c6[t][2] * rd[2] + bb, 0.f));
      h1p[(v0 + 3) * 168 + j] = f2bf(fmaxf(s3 + c6[t][3] * rd[3] + bb, 0.f));
    }
  }
  __syncthreads();

  // ---- phase 7: GEMM2  C2 = H1 @ [W2s | W2n]  (K=160, N=128) ----
  {
    const f32x4 z4 = {0.f, 0.f, 0.f, 0.f};
    f32x4 c7[2][4];
    #pragma unroll
    for (int t = 0; t < 2; ++t)
      #pragma unroll
      for (int m = 0; m < 4; ++m) c7[t][m] = z4;
    for (int kk = 0; kk < 5; ++kk) {
      bf16x8 a[4];
      #pragma unroll
      for (int m = 0; m < 4; ++m)
        a[m] = *(const bf16x8*)(smem + OFF_H1 + ((m * 16 + ln) * 168 + quad * 8) * 2 + kk * 64);
      bf16x8 b[2];
      #pragma unroll
      for (int t = 0; t < 2; ++t)
        b[t] = *(const bf16x8*)(W2T + ((w * 2 + t) * 16 + ln) * 168 + kk * 32 + quad * 8);
      #pragma unroll
      for (int t = 0; t < 2; ++t)
        #pragma unroll
        for (int m = 0; m < 4; ++m)
          c7[t][m] = mfma16(a[m], b[t], c7[t][m]);
    }
    // write S2 (f32) / T2t (bf16 transposed) into dead X region — disjoint from H1
    #pragma unroll
    for (int t = 0; t < 2; ++t) {
      const int ntg = w * 2 + t;   // wave-uniform: w0,w1 -> s2 ; w2,w3 -> t2
      #pragma unroll
      for (int m = 0; m < 4; ++m) {
        const int v0 = m * 16 + quad * 4;
        if (ntg < 4) {
          const int j2 = ntg * 16 + ln;
          float* s2p = (float*)(smem + OFF_S2);
          #pragma unroll
          for (int r = 0; r < 4; ++r) s2p[(v0 + r) * 66 + j2] = c7[t][m][r];
        } else {
          const int j2 = (ntg - 4) * 16 + ln;
          uint2 pk;
          pk.x = (u32)f2bf(c7[t][m][0]) | ((u32)f2bf(c7[t][m][1]) << 16);
          pk.y = (u32)f2bf(c7[t][m][2]) | ((u32)f2bf(c7[t][m][3]) << 16);
          *(uint2*)(smem + OFF_T2T + (j2 * 72 + v0) * 2) = pk;
        }
      }
    }
  }
  __syncthreads();

  // ---- phase 9: aggGEMM2 h2n = M @ t2 ; h2 = s2 + h2n*rdeg + b2 (f32) ----
  {
    const f32x4 z4 = {0.f, 0.f, 0.f, 0.f};
    f32x4 c9[4] = {z4, z4, z4, z4};
    const char* mb = smem + OFF_M + ((w * 16 + ln) * 72 + quad * 8) * 2;
    bf16x8 a0 = *(const bf16x8*)(mb);
    bf16x8 a1 = *(const bf16x8*)(mb + 64);
    #pragma unroll
    for (int t = 0; t < 4; ++t) {
      const char* tb = smem + OFF_T2T + ((t * 16 + ln) * 72 + quad * 8) * 2;
      bf16x8 b0 = *(const bf16x8*)(tb);
      bf16x8 b1f = *(const bf16x8*)(tb + 64);
      c9[t] = mfma16(a0, b0, c9[t]);
      c9[t] = mfma16(a1, b1f, c9[t]);
    }
    // h2 writes go to OFF_TT region (H1 dead); MFMA reads are OFF_X/OFF_M — disjoint
    const int v0 = w * 16 + quad * 4;
    float rd[4];
    #pragma unroll
    for (int r = 0; r < 4; ++r) rd[r] = rdeg[v0 + r];
    const float* s2p = (const float*)(smem + OFF_S2);
    float* h2p = (float*)(smem + OFF_H2);
    #pragma unroll
    for (int t = 0; t < 4; ++t) {
      const int j2 = t * 16 + ln;
      const float bb = b2g[j2];
      #pragma unroll
      for (int r = 0; r < 4; ++r)
        h2p[(v0 + r) * 66 + j2] = s2p[(v0 + r) * 66 + j2] + c9[t][r] * rd[r] + bb;
    }
  }
  __syncthreads();

  // ---- phase 10: gate + masked softmax ----
  {
    const int v = tid & 63, q = tid >> 6;
    const float* h2p = (const float*)(smem + OFF_H2);
    float s = 0.f;
    for (int j = q * 16; j < q * 16 + 16; ++j) s += h2p[v * 66 + j] * gw[j];
    red[q * 64 + v] = s;
  }
  __syncthreads();
  if (tid < 64) {
    float g = red[tid] + red[64 + tid] + red[128 + tid] + red[192 + tid] + gb[0];
    const bool val = wid[tid] > 0;
    g = val ? g : -1e30f;
    float mx = g;
    #pragma unroll
    for (int off = 32; off; off >>= 1) mx = fmaxf(mx, __shfl_xor(mx, off));
    float e = val ? __expf(g - mx) : 0.f;
    float ssum = e;
    #pragma unroll
    for (int off = 32; off; off >>= 1) ssum += __shfl_xor(ssum, off);
    attn[tid] = e / ssum;
  }
  __syncthreads();

  // ---- phase 11: pooled feature out[o] = sum_v attn[v] * h2[v][o] ----
  {
    const float av = attn[lane];
    const float* h2p = (const float*)(smem + OFF_H2);
    for (int o = w; o < 64; o += 4) {
      float x = av * h2p[lane * 66 + o];
      #pragma unroll
      for (int off = 32; off; off >>= 1) x += __shfl_xor(x, off);
      if (lane == 0) featout[(size_t)n * 64 + o] = x;
    }
  }
}

// ---------------- weight prep: transpose + pad + bf16 ----------------
__global__ void prep_w1(const float* Wn, const float* Ws, u16* dst) {
  int idx = blockIdx.x * 256 + threadIdx.x;
  if (idx >= W1_ROWS * W1_KP) return;
  int nn = idx / W1_KP, k = idx - nn * W1_KP;
  float v = 0.f;
  if (k < 300) {
    if (nn < 150) v = Wn[k * 150 + nn];
    else if (nn >= 160 && nn < 310) v = Ws[k * 150 + (nn - 160)];
  }
  dst[idx] = f2bf(v);
}
__global__ void prep_w2(const float* Ws, const float* Wn, u16* dst) {
  int idx = blockIdx.x * 256 + threadIdx.x;
  if (idx >= W2_ROWS * W2_KP) return;
  int nn = idx / W2_KP, k = idx - nn * W2_KP;
  float v = 0.f;
  if (k < 150) v = (nn < 64) ? Ws[k * 64 + nn] : Wn[k * 64 + (nn - 64)];
  dst[idx] = f2bf(v);
}

// ---------------- classifier ----------------
__global__ __launch_bounds__(128) void cls_kernel(const float* semf, const float* synf,
                                                  const float* hsg,
                                                  const float* w1, const float* b1,
                                                  const float* w2, const float* b2,
                                                  float* out) {
  __shared__ float feat[32][192];
  __shared__ float hid[32][132];
  const int r0 = blockIdx.x * 32;
  for (int idx = threadIdx.x; idx < 32 * 192; idx += 128) {
    int r = idx / 192, c = idx % 192;
    float v;
    if (c < 64)        v = semf[(size_t)(r0 + r) * 64 + c];
    else if (c < 128)  v = synf[(size_t)(r0 + r) * 64 + (c - 64)];
    else               v = hsg [(size_t)(r0 + r) * 64 + (c - 128)];
    feat[r][c] = v;
  }
  __syncthreads();
  {
    const int j = threadIdx.x;
    float acc[32];
    float bb = b1[j];
    #pragma unroll
    for (int r = 0; r < 32; ++r) acc[r] = bb;
    for (int k = 0; k < 192; ++k) {
      float ww = w1[(size_t)k * 128 + j];
      #pragma unroll
      for (int r = 0; r < 32; ++r) acc[r] += feat[r][k] * ww;
    }
    #pragma unroll
    for (int r = 0; r < 32; ++r) hid[r][j] = fmaxf(acc[r], 0.0f);
  }
  __syncthreads();
  if (threadIdx.x < 64) {
    const int r = threadIdx.x >> 1, o = threadIdx.x & 1;
    float a = b2[o];
    for (int h = 0; h < 128; ++h) a += hid[r][h] * w2[h * 2 + o];
    out[(size_t)(r0 + r) * 2 + o] = a;
  }
}

extern "C" void kernel_launch(void* const* d_in, const int* in_sizes, int n_in,
                              void* d_out, int out_size, void* d_ws, size_t ws_size,
                              hipStream_t stream) {
  GParams P;
  P.words     = (const int*)d_in[0];
  P.syn_words = (const int*)d_in[1];
  P.syn_adj   = (const int*)d_in[2];
  const float* hsg = (const float*)d_in[3];
  P.embed   = (const float*)d_in[4];
  const float* sem_W1s = (const float*)d_in[5];
  const float* sem_W1n = (const float*)d_in[6];
  P.sem_b1  = (const float*)d_in[7];
  const float* sem_W2s = (const float*)d_in[8];
  const float* sem_W2n = (const float*)d_in[9];
  P.sem_b2  = (const float*)d_in[10];
  P.sem_gw  = (const float*)d_in[11];
  P.sem_gb  = (const float*)d_in[12];
  const float* syn_W1s = (const float*)d_in[13];
  const float* syn_W1n = (const float*)d_in[14];
  P.syn_b1  = (const float*)d_in[15];
  const float* syn_W2s = (const float*)d_in[16];
  const float* syn_W2n = (const float*)d_in[17];
  P.syn_b2  = (const float*)d_in[18];
  P.syn_gw  = (const float*)d_in[19];
  P.syn_gb  = (const float*)d_in[20];
  const float* cls_w1 = (const float*)d_in[21];
  const float* cls_b1 = (const float*)d_in[22];
  const float* cls_w2 = (const float*)d_in[23];
  const float* cls_b2 = (const float*)d_in[24];

  float* semf = (float*)d_ws;                       // [NS][64]
  float* synf = semf + (size_t)NS * 64;             // [NS][64]  (4 MB total)
  u16* w1t_sem = (u16*)((char*)d_ws + (size_t)4 * 1024 * 1024);
  u16* w1t_syn = w1t_sem + W1_ROWS * W1_KP;
  u16* w2t_sem = w1t_syn + W1_ROWS * W1_KP;
  u16* w2t_syn = w2t_sem + W2_ROWS * W2_KP;
  P.semf = semf; P.synf = synf;
  P.w1t_sem = w1t_sem; P.w1t_syn = w1t_syn;
  P.w2t_sem = w2t_sem; P.w2t_syn = w2t_syn;

  const int g1 = (W1_ROWS * W1_KP + 255) / 256;
  const int g2 = (W2_ROWS * W2_KP + 255) / 256;
  prep_w1<<<g1, 256, 0, stream>>>(sem_W1n, sem_W1s, w1t_sem);
  prep_w1<<<g1, 256, 0, stream>>>(syn_W1n, syn_W1s, w1t_syn);
  prep_w2<<<g2, 256, 0, stream>>>(sem_W2s, sem_W2n, w2t_sem);
  prep_w2<<<g2, 256, 0, stream>>>(syn_W2s, syn_W2n, w2t_syn);

  sage_kernel<<<2 * NS, 256, 0, stream>>>(P);
  cls_kernel<<<NS / 32, 128, 0, stream>>>(semf, synf, hsg, cls_w1, cls_b1,
                                          cls_w2, cls_b2, (float*)d_out);
}

// Round 3
// 882.880 us; speedup vs baseline: 7.4498x; 1.2771x over previous
//
#include <hip/hip_runtime.h>

#define NS 8192
#define L  50

typedef unsigned short u16;
typedef unsigned int   u32;
typedef __attribute__((ext_vector_type(8))) __bf16 bf16x8;
typedef __attribute__((ext_vector_type(4))) float  f32x4;

// ---------------- LDS layout (bytes) ----------------
// live ranges: X(gather,Gram,GEMM1) dies at sync3; Tt(sync3..agg1) aliases X;
// T2t(GEMM2..agg2) aliases Tt; attn aliases T2t (after sync7);
// H1(agg1-epi..GEMM2) aliases X tail; red aliases H1 (after sync6);
// diag aliases M region (diag dead before M written).
#define OFF_X    0        // X bf16 [64][328] = 41984
#define OFF_TT   0        // Tt bf16 [160][68] = 21760
#define OFF_T2T  0        // T2t bf16 [64][68] = 8704
#define OFF_ATTN 0        // attn f32 [64] (after sync7)
#define OFF_H1   21760    // H1 bf16 [64][168] = 21504 -> 43264
#define OFF_RED  21760    // red f32 [64][17] = 4352 (after sync6)
#define OFF_M    43264    // M bf16 [64][72] = 9216 -> 52480
#define OFF_DIAG 43264    // diag f32[64] (dead before M written)
#define OFF_WID  52480
#define OFF_CLO  52736
#define OFF_CHI  52992
#define OFF_RDEG 53248
#define SMEM_SZ  53504    // -> 3 blocks/CU (3*53760 rounded <= 160KB)

#define XSTR  328   // elems; 656B rows, 16B aligned, ==4 mod 32 banks (2-way)
#define TSTR  68    // elems; 136B rows, 8B aligned (b64-pair frag loads)
#define H1STR 168   // elems; 336B rows, 16B aligned
#define MSTR  72    // elems; 144B rows, 16B aligned

// padded weight tables in ws
#define W1_ROWS 320   // rows [0,150)=W1n(col j), [160,310)=W1s; rest 0
#define W1_KP   328
#define W2_ROWS 128   // rows [0,64)=W2s, [64,128)=W2n
#define W2_KP   168

__device__ __forceinline__ u16 f2bf(float f) {
  u32 u = __float_as_uint(f);
  u += 0x7fffu + ((u >> 16) & 1u);   // RNE
  return (u16)(u >> 16);
}
__device__ __forceinline__ float bf2f(u16 h) {
  return __uint_as_float(((u32)h) << 16);
}
__device__ __forceinline__ f32x4 mfma16(bf16x8 a, bf16x8 b, f32x4 c) {
  return __builtin_amdgcn_mfma_f32_16x16x32_bf16(a, b, c, 0, 0, 0);
}
__device__ __forceinline__ uint2 pack4bf(f32x4 c) {
  uint2 p;
  p.x = (u32)f2bf(c[0]) | ((u32)f2bf(c[1]) << 16);
  p.y = (u32)f2bf(c[2]) | ((u32)f2bf(c[3]) << 16);
  return p;
}
union BF8U { bf16x8 v; uint4 u; };
__device__ __forceinline__ bf16x8 ld_bf8_b64pair(const u16* p) {
  uint2 a = *(const uint2*)p;
  uint2 b = *(const uint2*)(p + 4);
  BF8U r; r.u = make_uint4(a.x, a.y, b.x, b.y);
  return r.v;
}

struct GParams {
  const int* words; const int* syn_words; const int* syn_adj;
  const float* embed;
  const float* sem_b1; const float* sem_b2; const float* sem_gw; const float* sem_gb;
  const float* syn_b1; const float* syn_b2; const float* syn_gw; const float* syn_gb;
  const u16* w1t_sem; const u16* w1t_syn; const u16* w2t_sem; const u16* w2t_syn;
  float* semf; float* synf;
};

// One block per (sentence, graph). [0,NS)=semantic, [NS,2NS)=syntax.
__global__ __launch_bounds__(256, 3) void sage_kernel(GParams P) {
  __shared__ __align__(16) char smem[SMEM_SZ];
  int*   wid   = (int*)(smem + OFF_WID);
  u32*   clo   = (u32*)(smem + OFF_CLO);
  u32*   chi   = (u32*)(smem + OFF_CHI);
  float* rdegp = (float*)(smem + OFF_RDEG);
  float* diag  = (float*)(smem + OFF_DIAG);

  const int tid  = threadIdx.x;
  const int lane = tid & 63;
  const int w    = tid >> 6;
  const int ln   = lane & 15;
  const int quad = lane >> 4;

  const bool semg = (blockIdx.x < NS);
  const int  n    = semg ? blockIdx.x : (blockIdx.x - NS);

  const int*   wsrc = semg ? P.words   : P.syn_words;
  const u16*   W1T  = semg ? P.w1t_sem : P.w1t_syn;
  const u16*   W2T  = semg ? P.w2t_sem : P.w2t_syn;
  const float* b1g  = semg ? P.sem_b1  : P.syn_b1;
  const float* b2g  = semg ? P.sem_b2  : P.syn_b2;
  const float* gw   = semg ? P.sem_gw  : P.syn_gw;
  const float* gb   = semg ? P.sem_gb  : P.syn_gb;
  float* featout    = semg ? P.semf    : P.synf;

  // j-tile set per wave: {w, w+4, 8+(w&1)} — third tile duplicated for waves
  // 2,3 (bitwise-identical recompute keeps barriers convergent).
  const int jts[3] = {w, w + 4, 8 + (w & 1)};

  // ---- P0: word ids + mask init ----
  if (tid < 64) {
    wid[tid] = (tid < L) ? wsrc[(size_t)n * L + tid] : 0;
    clo[tid] = 0u; chi[tid] = 0u;
  }
  __syncthreads();

  // ---- P1: gather X bf16 [64][328]; invalid rows & pad cols -> 0 ----
  for (int i = 0; i < 16; ++i) {
    const int v = w + 4 * i;          // wave w owns rows w,w+4,...
    const int word = wid[v];
    const float* src = P.embed + (size_t)word * 300;
    u16* xrow = (u16*)(smem + OFF_X) + v * XSTR;
    for (int l = lane; l < 82; l += 64) {
      uint2 pk = make_uint2(0u, 0u);
      if (word > 0 && l < 75) {
        float4 f = *(const float4*)(src + l * 4);   // rows 16B-aligned (1200B)
        pk.x = (u32)f2bf(f.x) | ((u32)f2bf(f.y) << 16);
        pk.y = (u32)f2bf(f.z) | ((u32)f2bf(f.w) << 16);
      }
      *(uint2*)(xrow + l * 4) = pk;
    }
  }
  __syncthreads();

  // ---- P2: adjacency column bitmasks ----
  if (semg) {
    const f32x4 z4 = {0.f, 0.f, 0.f, 0.f};
    f32x4 g[4] = {z4, z4, z4, z4};
    const char* xb = smem + OFF_X;
    const int arow = (w * 16 + ln) * (XSTR * 2) + quad * 16;
    for (int kk = 0; kk < 10; ++kk) {
      bf16x8 a = *(const bf16x8*)(xb + arow + kk * 64);
      #pragma unroll
      for (int nt = 0; nt < 4; ++nt) {
        bf16x8 b = *(const bf16x8*)(xb + (nt * 16 + ln) * (XSTR * 2) + quad * 16 + kk * 64);
        g[nt] = mfma16(a, b, g[nt]);
      }
    }
    // diagonal (u==v requires nt==w, ln in [quad*4, quad*4+4))
    {
      const int r = ln - quad * 4;
      if (r >= 0 && r < 4) {
        #pragma unroll
        for (int nt = 0; nt < 4; ++nt) {
          if (nt == w) {
            float val = (r == 0) ? g[nt][0] : (r == 1) ? g[nt][1]
                      : (r == 2) ? g[nt][2] : g[nt][3];
            diag[w * 16 + ln] = val;
          }
        }
      }
    }
    __syncthreads();
    if (tid < 64) { float dd = diag[tid]; diag[tid] = 1.0f / sqrtf(fmaxf(dd, 1e-12f)); }
    __syncthreads();
    {
      const int ubase = w * 16 + quad * 4;
      float ru[4]; int uok[4];
      #pragma unroll
      for (int r = 0; r < 4; ++r) { ru[r] = diag[ubase + r]; uok[r] = wid[ubase + r] > 0; }
      #pragma unroll
      for (int nt = 0; nt < 4; ++nt) {
        const int v = nt * 16 + ln;
        const float rv = diag[v];
        const bool vok = wid[v] > 0;
        u32 nib = 0u;
        #pragma unroll
        for (int r = 0; r < 4; ++r) {
          float c = g[nt][r] * ru[r] * rv;
          if (vok && uok[r] && c > 0.7f) nib |= (1u << r);
        }
        if (nib) {
          if (ubase < 32) atomicOr(&clo[v], nib << ubase);
          else            atomicOr(&chi[v], nib << (ubase - 32));
        }
      }
    }
  } else {
    const int* abase = P.syn_adj + (size_t)n * (L * L);
    for (int v = w; v < L; v += 4) {
      int val = (lane < L) ? abase[lane * L + v] : 0;
      unsigned long long m = __ballot(val != 0);
      if (lane == 0) { clo[v] = (u32)m; chi[v] = (u32)(m >> 32); }
    }
  }
  __syncthreads();

  // ---- P3: rdeg + M[v][u] bf16 build + GEMM1 k-loop (regs) ----
  if (tid < 64) {
    int dg = __popc(clo[tid]) + __popc(chi[tid]);
    rdegp[tid] = 1.0f / (float)(dg > 0 ? dg : 1);
  }
  {
    // thread (v=lane, half=w) builds 16 cols of M row v, b64 writes
    const int v = lane, half = w;
    const u32 src = (half < 2) ? clo[v] : chi[v];
    const int sh = (half & 1) * 16;
    u16* Mrow = (u16*)(smem + OFF_M) + v * MSTR + half * 16;
    #pragma unroll
    for (int c = 0; c < 4; ++c) {
      uint2 pk;
      u32 b0 = (src >> (sh + 4 * c + 0)) & 1u;
      u32 b1 = (src >> (sh + 4 * c + 1)) & 1u;
      u32 b2 = (src >> (sh + 4 * c + 2)) & 1u;
      u32 b3 = (src >> (sh + 4 * c + 3)) & 1u;
      pk.x = (b0 ? 0x3F80u : 0u) | (b1 ? 0x3F800000u : 0u);
      pk.y = (b2 ? 0x3F80u : 0u) | (b3 ? 0x3F800000u : 0u);
      *(uint2*)(Mrow + 4 * c) = pk;
    }
  }

  const f32x4 z4 = {0.f, 0.f, 0.f, 0.f};
  f32x4 tacc[3][4], sacc[3][4];
  #pragma unroll
  for (int i = 0; i < 3; ++i)
    #pragma unroll
    for (int m = 0; m < 4; ++m) { tacc[i][m] = z4; sacc[i][m] = z4; }
  {
    const char* xb = smem + OFF_X;
    for (int kk = 0; kk < 10; ++kk) {
      bf16x8 x[4];
      #pragma unroll
      for (int m = 0; m < 4; ++m)
        x[m] = *(const bf16x8*)(xb + (m * 16 + ln) * (XSTR * 2) + quad * 16 + kk * 64);
      bf16x8 bn[3], as[3];
      #pragma unroll
      for (int i = 0; i < 3; ++i) {
        const int jt = jts[i];
        bn[i] = *(const bf16x8*)(W1T + (size_t)(jt * 16 + ln) * W1_KP + kk * 32 + quad * 8);
        as[i] = *(const bf16x8*)(W1T + (size_t)((jt + 10) * 16 + ln) * W1_KP + kk * 32 + quad * 8);
      }
      #pragma unroll
      for (int i = 0; i < 3; ++i)
        #pragma unroll
        for (int m = 0; m < 4; ++m) {
          tacc[i][m] = mfma16(x[m], bn[i], tacc[i][m]);   // D[v][j]: t-part
          sacc[i][m] = mfma16(as[i], x[m], sacc[i][m]);   // D[j][v]: s-part (regs)
        }
    }
  }
  __syncthreads();   // sync3: X reads done everywhere; M/rdeg visible

  // ---- P4: write Tt[j][u] (aliases X; each wave writes only its own rows) ----
  {
    u16* tt = (u16*)(smem + OFF_TT);
    #pragma unroll
    for (int i = 0; i < 3; ++i) {
      const int jt = jts[i];
      #pragma unroll
      for (int m = 0; m < 4; ++m) {
        const int v0 = m * 16 + quad * 4;
        *(uint2*)(tt + (jt * 16 + ln) * TSTR + v0) = pack4bf(tacc[i][m]);
      }
    }
  }

  // ---- P5: agg1 = Tt x M (swapped: D[j][v]); epilogue -> H1[v][j] b64 ----
  bf16x8 mb0[4], mb1[4];
  {
    const u16* Mp = (const u16*)(smem + OFF_M);
    #pragma unroll
    for (int vt = 0; vt < 4; ++vt) {
      mb0[vt] = *(const bf16x8*)(Mp + (vt * 16 + ln) * MSTR + quad * 8);
      mb1[vt] = *(const bf16x8*)(Mp + (vt * 16 + ln) * MSTR + quad * 8 + 32);
    }
  }
  float rd[4];
  #pragma unroll
  for (int vt = 0; vt < 4; ++vt) rd[vt] = rdegp[vt * 16 + ln];
  {
    const u16* tt = (const u16*)(smem + OFF_TT);
    u16* h1p = (u16*)(smem + OFF_H1);
    #pragma unroll
    for (int i = 0; i < 3; ++i) {
      const int jt = jts[i];
      f32x4 gacc[4] = {z4, z4, z4, z4};
      const u16* tb = tt + (jt * 16 + ln) * TSTR + quad * 8;
      bf16x8 ta0 = ld_bf8_b64pair(tb);
      bf16x8 ta1 = ld_bf8_b64pair(tb + 32);
      #pragma unroll
      for (int vt = 0; vt < 4; ++vt) {
        gacc[vt] = mfma16(ta0, mb0[vt], gacc[vt]);
        gacc[vt] = mfma16(ta1, mb1[vt], gacc[vt]);
      }
      const int j0 = jt * 16 + quad * 4;
      float bv[4];
      #pragma unroll
      for (int r = 0; r < 4; ++r) { int j = j0 + r; bv[r] = (j < 150) ? b1g[j] : 0.f; }
      #pragma unroll
      for (int vt = 0; vt < 4; ++vt) {
        const int v = vt * 16 + ln;
        f32x4 hv;
        #pragma unroll
        for (int r = 0; r < 4; ++r)
          hv[r] = fmaxf(sacc[i][vt][r] + gacc[vt][r] * rd[vt] + bv[r], 0.f);
        *(uint2*)(h1p + v * H1STR + j0) = pack4bf(hv);
      }
    }
  }
  __syncthreads();   // sync5: all H1 written

  // ---- P6: GEMM2 (s2 swapped in regs; t2 -> T2t self-rows) + agg2 + h2 regs ----
  f32x4 s2acc[4] = {z4, z4, z4, z4};
  f32x4 h2v[4];
  {
    f32x4 t2acc[4] = {z4, z4, z4, z4};
    const u16* h1p = (const u16*)(smem + OFF_H1);
    for (int kk = 0; kk < 5; ++kk) {
      bf16x8 h[4];
      #pragma unroll
      for (int t4 = 0; t4 < 4; ++t4)
        h[t4] = *(const bf16x8*)(h1p + (t4 * 16 + ln) * H1STR + kk * 32 + quad * 8);
      bf16x8 a2  = *(const bf16x8*)(W2T + (size_t)(w * 16 + ln) * W2_KP + kk * 32 + quad * 8);
      bf16x8 b2f = *(const bf16x8*)(W2T + (size_t)((4 + w) * 16 + ln) * W2_KP + kk * 32 + quad * 8);
      #pragma unroll
      for (int vt = 0; vt < 4; ++vt) {
        s2acc[vt] = mfma16(a2, h[vt], s2acc[vt]);   // D[j2][v]
        t2acc[vt] = mfma16(h[vt], b2f, t2acc[vt]);  // D[v][j2]
      }
    }
    u16* t2t = (u16*)(smem + OFF_T2T);
    #pragma unroll
    for (int m = 0; m < 4; ++m) {
      const int v0 = m * 16 + quad * 4;
      *(uint2*)(t2t + (w * 16 + ln) * TSTR + v0) = pack4bf(t2acc[m]);
    }
    // agg2: A = T2t (self rows), B = M
    f32x4 g2[4] = {z4, z4, z4, z4};
    const u16* t2b = t2t + (w * 16 + ln) * TSTR + quad * 8;
    bf16x8 u0 = ld_bf8_b64pair(t2b);
    bf16x8 u1 = ld_bf8_b64pair(t2b + 32);
    #pragma unroll
    for (int vt = 0; vt < 4; ++vt) {
      g2[vt] = mfma16(u0, mb0[vt], g2[vt]);
      g2[vt] = mfma16(u1, mb1[vt], g2[vt]);
    }
    const int j0q = w * 16 + quad * 4;
    float b2v[4];
    #pragma unroll
    for (int r = 0; r < 4; ++r) b2v[r] = b2g[j0q + r];
    #pragma unroll
    for (int vt = 0; vt < 4; ++vt)
      #pragma unroll
      for (int r = 0; r < 4; ++r)
        h2v[vt][r] = s2acc[vt][r] + g2[vt][r] * rd[vt] + b2v[r];
  }
  __syncthreads();   // sync6: H1/T2t/Tt reads all done -> red region free

  // ---- P7: gate partials -> red[v][16] ----
  {
    const int j0q = w * 16 + quad * 4;
    float gwv[4];
    #pragma unroll
    for (int r = 0; r < 4; ++r) gwv[r] = gw[j0q + r];
    float* redp = (float*)(smem + OFF_RED);
    #pragma unroll
    for (int vt = 0; vt < 4; ++vt) {
      float p = h2v[vt][0] * gwv[0] + h2v[vt][1] * gwv[1]
              + h2v[vt][2] * gwv[2] + h2v[vt][3] * gwv[3];
      redp[(vt * 16 + ln) * 17 + (w * 4 + quad)] = p;
    }
  }
  __syncthreads();   // sync7

  // ---- P8: masked softmax over gates (wave 0) ----
  if (tid < 64) {
    const float* redp = (const float*)(smem + OFF_RED);
    float g = gb[0];
    #pragma unroll
    for (int i = 0; i < 16; ++i) g += redp[tid * 17 + i];
    const bool val = wid[tid] > 0;
    g = val ? g : -1e30f;
    float mx = g;
    #pragma unroll
    for (int off = 32; off; off >>= 1) mx = fmaxf(mx, __shfl_xor(mx, off));
    float e = val ? __expf(g - mx) : 0.f;
    float ssum = e;
    #pragma unroll
    for (int off = 32; off; off >>= 1) ssum += __shfl_xor(ssum, off);
    ((float*)(smem + OFF_ATTN))[tid] = e / ssum;
  }
  __syncthreads();   // sync8

  // ---- P9: pooled feature out[j2] = sum_v attn[v] h2[v][j2] ----
  {
    const float* attnp = (const float*)(smem + OFF_ATTN);
    float av[4];
    #pragma unroll
    for (int vt = 0; vt < 4; ++vt) av[vt] = attnp[vt * 16 + ln];
    float xr[4];
    #pragma unroll
    for (int r = 0; r < 4; ++r) {
      float x = av[0] * h2v[0][r] + av[1] * h2v[1][r]
              + av[2] * h2v[2][r] + av[3] * h2v[3][r];
      #pragma unroll
      for (int off = 1; off < 16; off <<= 1) x += __shfl_xor(x, off);
      xr[r] = x;
    }
    if (ln == 0) {
      const int j0q = w * 16 + quad * 4;
      *(float4*)(featout + (size_t)n * 64 + j0q) = make_float4(xr[0], xr[1], xr[2], xr[3]);
    }
  }
}

// ---------------- weight prep: transpose + pad + bf16 ----------------
__global__ void prep_w1(const float* Wn, const float* Ws, u16* dst) {
  int idx = blockIdx.x * 256 + threadIdx.x;
  if (idx >= W1_ROWS * W1_KP) return;
  int nn = idx / W1_KP, k = idx - nn * W1_KP;
  float v = 0.f;
  if (k < 300) {
    if (nn < 150) v = Wn[k * 150 + nn];
    else if (nn >= 160 && nn < 310) v = Ws[k * 150 + (nn - 160)];
  }
  dst[idx] = f2bf(v);
}
__global__ void prep_w2(const float* Ws, const float* Wn, u16* dst) {
  int idx = blockIdx.x * 256 + threadIdx.x;
  if (idx >= W2_ROWS * W2_KP) return;
  int nn = idx / W2_KP, k = idx - nn * W2_KP;
  float v = 0.f;
  if (k < 150) v = (nn < 64) ? Ws[k * 64 + nn] : Wn[k * 64 + (nn - 64)];
  dst[idx] = f2bf(v);
}

// ---------------- classifier ----------------
__global__ __launch_bounds__(128) void cls_kernel(const float* semf, const float* synf,
                                                  const float* hsg,
                                                  const float* w1, const float* b1,
                                                  const float* w2, const float* b2,
                                                  float* out) {
  __shared__ float feat[32][192];
  __shared__ float hid[32][132];
  const int r0 = blockIdx.x * 32;
  for (int idx = threadIdx.x; idx < 32 * 192; idx += 128) {
    int r = idx / 192, c = idx % 192;
    float v;
    if (c < 64)        v = semf[(size_t)(r0 + r) * 64 + c];
    else if (c < 128)  v = synf[(size_t)(r0 + r) * 64 + (c - 64)];
    else               v = hsg [(size_t)(r0 + r) * 64 + (c - 128)];
    feat[r][c] = v;
  }
  __syncthreads();
  {
    const int j = threadIdx.x;
    float acc[32];
    float bb = b1[j];
    #pragma unroll
    for (int r = 0; r < 32; ++r) acc[r] = bb;
    for (int k = 0; k < 192; ++k) {
      float ww = w1[(size_t)k * 128 + j];
      #pragma unroll
      for (int r = 0; r < 32; ++r) acc[r] += feat[r][k] * ww;
    }
    #pragma unroll
    for (int r = 0; r < 32; ++r) hid[r][j] = fmaxf(acc[r], 0.0f);
  }
  __syncthreads();
  if (threadIdx.x < 64) {
    const int r = threadIdx.x >> 1, o = threadIdx.x & 1;
    float a = b2[o];
    for (int h = 0; h < 128; ++h) a += hid[r][h] * w2[h * 2 + o];
    out[(size_t)(r0 + r) * 2 + o] = a;
  }
}

extern "C" void kernel_launch(void* const* d_in, const int* in_sizes, int n_in,
                              void* d_out, int out_size, void* d_ws, size_t ws_size,
                              hipStream_t stream) {
  GParams P;
  P.words     = (const int*)d_in[0];
  P.syn_words = (const int*)d_in[1];
  P.syn_adj   = (const int*)d_in[2];
  const float* hsg = (const float*)d_in[3];
  P.embed   = (const float*)d_in[4];
  const float* sem_W1s = (const float*)d_in[5];
  const float* sem_W1n = (const float*)d_in[6];
  P.sem_b1  = (const float*)d_in[7];
  const float* sem_W2s = (const float*)d_in[8];
  const float* sem_W2n = (const float*)d_in[9];
  P.sem_b2  = (const float*)d_in[10];
  P.sem_gw  = (const float*)d_in[11];
  P.sem_gb  = (const float*)d_in[12];
  const float* syn_W1s = (const float*)d_in[13];
  const float* syn_W1n = (const float*)d_in[14];
  P.syn_b1  = (const float*)d_in[15];
  const float* syn_W2s = (const float*)d_in[16];
  const float* syn_W2n = (const float*)d_in[17];
  P.syn_b2  = (const float*)d_in[18];
  P.syn_gw  = (const float*)d_in[19];
  P.syn_gb  = (const float*)d_in[20];
  const float* cls_w1 = (const float*)d_in[21];
  const float* cls_b1 = (const float*)d_in[22];
  const float* cls_w2 = (const float*)d_in[23];
  const float* cls_b2 = (const float*)d_in[24];

  float* semf = (float*)d_ws;                       // [NS][64]
  float* synf = semf + (size_t)NS * 64;             // [NS][64]  (4 MB total)
  u16* w1t_sem = (u16*)((char*)d_ws + (size_t)4 * 1024 * 1024);
  u16* w1t_syn = w1t_sem + W1_ROWS * W1_KP;
  u16* w2t_sem = w1t_syn + W1_ROWS * W1_KP;
  u16* w2t_syn = w2t_sem + W2_ROWS * W2_KP;
  P.semf = semf; P.synf = synf;
  P.w1t_sem = w1t_sem; P.w1t_syn = w1t_syn;
  P.w2t_sem = w2t_sem; P.w2t_syn = w2t_syn;

  const int g1 = (W1_ROWS * W1_KP + 255) / 256;
  const int g2 = (W2_ROWS * W2_KP + 255) / 256;
  prep_w1<<<g1, 256, 0, stream>>>(sem_W1n, sem_W1s, w1t_sem);
  prep_w1<<<g1, 256, 0, stream>>>(syn_W1n, syn_W1s, w1t_syn);
  prep_w2<<<g2, 256, 0, stream>>>(sem_W2s, sem_W2n, w2t_sem);
  prep_w2<<<g2, 256, 0, stream>>>(syn_W2s, syn_W2n, w2t_syn);

  sage_kernel<<<2 * NS, 256, 0, stream>>>(P);
  cls_kernel<<<NS / 32, 128, 0, stream>>>(semf, synf, hsg, cls_w1, cls_b1,
                                          cls_w2, cls_b2, (float*)d_out);
}